// Round 2
// baseline (2900.352 us; speedup 1.0000x reference)
//
#include <hip/hip_runtime.h>
#include <stdint.h>
#include <math.h>

#define N_NODES 100000
#define N_EDGES 1600000

// ---------------- Threefry-2x32 (JAX-compatible) ----------------
__device__ __host__ __forceinline__ uint32_t rotl32(uint32_t v, int d) {
  return (v << d) | (v >> (32 - d));
}

__device__ __host__ __forceinline__ void threefry2x32(uint32_t k0, uint32_t k1,
                                                      uint32_t x0, uint32_t x1,
                                                      uint32_t& o0, uint32_t& o1) {
  uint32_t ks0 = k0, ks1 = k1, ks2 = k0 ^ k1 ^ 0x1BD11BDAu;
  x0 += ks0; x1 += ks1;
#define TF_R(r) { x0 += x1; x1 = rotl32(x1, r); x1 ^= x0; }
  TF_R(13) TF_R(15) TF_R(26) TF_R(6)
  x0 += ks1; x1 += ks2 + 1u;
  TF_R(17) TF_R(29) TF_R(16) TF_R(24)
  x0 += ks2; x1 += ks0 + 2u;
  TF_R(13) TF_R(15) TF_R(26) TF_R(6)
  x0 += ks0; x1 += ks1 + 3u;
  TF_R(17) TF_R(29) TF_R(16) TF_R(24)
  x0 += ks1; x1 += ks2 + 4u;
  TF_R(13) TF_R(15) TF_R(26) TF_R(6)
  x0 += ks2; x1 += ks0 + 5u;
#undef TF_R
  o0 = x0; o1 = x1;
}

// Partitionable-threefry dropout mask (JAX >= 0.4.36 default):
// bits(idx) = o0 ^ o1 of threefry(key; hi(idx)=0, lo(idx)=idx)
// u = bitcast((bits>>9)|0x3f800000)-1 ; keep iff u < 0.5 ; scale 1/(1-p)=2
__device__ __forceinline__ float drop_scale(uint32_t idx, uint32_t k0, uint32_t k1) {
  uint32_t o0, o1;
  threefry2x32(k0, k1, 0u, idx, o0, o1);
  uint32_t bits = o0 ^ o1;
  float u = __uint_as_float((bits >> 9) | 0x3f800000u) - 1.0f;
  return (u < 0.5f) ? 2.0f : 0.0f;
}

// ---------------- Edge dtype detect + canonicalize ----------------
// If edge_index arrives as raw int64, odd 32-bit words of the first half
// (row array) are high-words == 0. If int32, they are genuine row values.
__global__ __launch_bounds__(256) void detect_kernel(const int* __restrict__ ei,
                                                     int* __restrict__ found_nonzero) {
  int idx = blockIdx.x * 256 + threadIdx.x;  // 0..2047
  size_t j = (size_t)idx * 781;              // < 1.6M
  if (ei[2 * j + 1] != 0) atomicOr(found_nonzero, 1);
}

__global__ __launch_bounds__(256) void convert_kernel(const int* __restrict__ ei,
                                                      const int* __restrict__ found_nonzero,
                                                      int* __restrict__ row32,
                                                      int* __restrict__ col32) {
  int e = blockIdx.x * 256 + threadIdx.x;
  if (e >= N_EDGES) return;
  if (*found_nonzero) {  // int32 layout
    row32[e] = ei[e];
    col32[e] = ei[N_EDGES + e];
  } else {               // int64 layout: take low words
    row32[e] = ei[2 * (size_t)e];
    col32[e] = ei[2 * ((size_t)N_EDGES + (size_t)e)];
  }
}

// ---------------- Graph preprocessing ----------------
__global__ __launch_bounds__(256) void deg_kernel(const int* __restrict__ col,
                                                  int* __restrict__ deg) {
  int e = blockIdx.x * 256 + threadIdx.x;
  if (e < N_EDGES) atomicAdd(&deg[col[e]], 1);
}

__global__ __launch_bounds__(256) void dis_kernel(const int* __restrict__ deg,
                                                  float* __restrict__ dis) {
  int n = blockIdx.x * 256 + threadIdx.x;
  if (n < N_NODES) {
    int d = deg[n];
    dis[n] = (d > 0) ? (1.0f / sqrtf((float)d)) : 0.0f;
  }
}

__global__ __launch_bounds__(1024) void scan_kernel(const int* __restrict__ deg,
                                                    int* __restrict__ ptr, int n) {
  __shared__ int buf[1024];
  __shared__ int carry_s;
  int tid = threadIdx.x;
  if (tid == 0) carry_s = 0;
  __syncthreads();
  for (int base = 0; base < n; base += 1024) {
    int v = (base + tid < n) ? deg[base + tid] : 0;
    buf[tid] = v;
    __syncthreads();
    for (int ofs = 1; ofs < 1024; ofs <<= 1) {
      int t = (tid >= ofs) ? buf[tid - ofs] : 0;
      __syncthreads();
      buf[tid] += t;
      __syncthreads();
    }
    int carry = carry_s;
    if (base + tid < n) ptr[base + tid] = carry + buf[tid] - v;  // exclusive
    __syncthreads();
    if (tid == 0) carry_s = carry + buf[1023];
    __syncthreads();
  }
  if (tid == 0) ptr[n] = carry_s;
}

__global__ __launch_bounds__(256) void fill_kernel(const int* __restrict__ row,
                                                   const int* __restrict__ col,
                                                   const float* __restrict__ dis,
                                                   const int* __restrict__ rptr,
                                                   int* cursor,
                                                   int* __restrict__ erow,
                                                   float* __restrict__ enorm) {
  int e = blockIdx.x * 256 + threadIdx.x;
  if (e < N_EDGES) {
    int c = col[e], r = row[e];
    int p = atomicAdd(&cursor[c], 1);
    int idx = rptr[c] + p;
    erow[idx] = r;
    enorm[idx] = dis[r] * dis[c];
  }
}

// ---------------- Dense matmul: y_k = h @ W_k^T (k=0..3), bias into y0 --------
template <int DIN, int DOUT>
__global__ __launch_bounds__(256) void matmul4_kernel(
    const float* __restrict__ h, const float* __restrict__ W,
    const float* __restrict__ bias,
    float* __restrict__ y0, float* __restrict__ y1,
    float* __restrict__ y2, float* __restrict__ y3) {
  __shared__ float hs[32][DIN + 1];  // +1 pad: conflict-free column reads
  int n0 = blockIdx.x * 32;
  for (int idx = threadIdx.x; idx < 32 * DIN; idx += 256) {
    int n = idx / DIN, i = idx - n * DIN;
    int gn = n0 + n;
    hs[n][i] = (gn < N_NODES) ? h[(size_t)gn * DIN + i] : 0.0f;
  }
  __syncthreads();
  int nsub = threadIdx.x & 31, oslot = threadIdx.x >> 5;
  int gn = n0 + nsub;
  if (gn >= N_NODES) return;
  for (int o = oslot; o < DOUT; o += 8) {
    const float* w0 = W + (size_t)(0 * DOUT + o) * DIN;
    const float* w1 = W + (size_t)(1 * DOUT + o) * DIN;
    const float* w2 = W + (size_t)(2 * DOUT + o) * DIN;
    const float* w3 = W + (size_t)(3 * DOUT + o) * DIN;
    float a0 = 0.f, a1 = 0.f, a2 = 0.f, a3 = 0.f;
#pragma unroll 4
    for (int i = 0; i < DIN; ++i) {
      float hv = hs[nsub][i];
      a0 = fmaf(hv, w0[i], a0);
      a1 = fmaf(hv, w1[i], a1);
      a2 = fmaf(hv, w2[i], a2);
      a3 = fmaf(hv, w3[i], a3);
    }
    size_t oi = (size_t)gn * DOUT + o;
    y0[oi] = a0 + bias[o];
    y1[oi] = a1;
    y2[oi] = a2;
    y3[oi] = a3;
  }
}

// ---------------- Propagation: out[c] = sum_e norm*z[row_e] + add[c] ----------
// EPI: 0 = none, 1 = dropout(key1), 2 = elu then dropout(key2)
// out may alias add (per-element read-then-write), never aliases z.
template <int D, int EPI>
__global__ __launch_bounds__(256) void prop_kernel(
    const float* __restrict__ z, const float* addb, float* out,
    const int* __restrict__ rptr, const int* __restrict__ erow,
    const float* __restrict__ enorm,
    uint32_t k0, uint32_t k1) {
  constexpr int LPN = (D >= 64) ? 64 : D;  // lanes per node
  constexpr int VEC = (D == 128) ? 2 : 1;  // floats per lane
  constexpr int NPB = 256 / LPN;           // nodes per block
  int lane = threadIdx.x % LPN;
  int nsub = threadIdx.x / LPN;
  int c = blockIdx.x * NPB + nsub;
  if (c >= N_NODES) return;
  int e0 = rptr[c], e1 = rptr[c + 1];
  float acc0 = 0.f, acc1 = 0.f;
  if (VEC == 2) {
    const float2* zz = (const float2*)z;
    for (int e = e0; e < e1; ++e) {
      int r = erow[e];
      float w = enorm[e];
      float2 v = zz[(size_t)r * 64 + lane];
      acc0 = fmaf(w, v.x, acc0);
      acc1 = fmaf(w, v.y, acc1);
    }
    size_t base = (size_t)c * 128 + 2 * lane;
    float2 a = ((const float2*)addb)[(size_t)c * 64 + lane];
    float v0 = acc0 + a.x, v1 = acc1 + a.y;
    if (EPI == 1) {
      v0 *= drop_scale((uint32_t)base, k0, k1);
      v1 *= drop_scale((uint32_t)base + 1, k0, k1);
    }
    ((float2*)out)[(size_t)c * 64 + lane] = make_float2(v0, v1);
  } else {
    for (int e = e0; e < e1; ++e) {
      int r = erow[e];
      float w = enorm[e];
      acc0 = fmaf(w, z[(size_t)r * D + lane], acc0);
    }
    size_t idx = (size_t)c * D + lane;
    float v = acc0 + addb[idx];
    if (EPI == 2) {
      v = (v > 0.f) ? v : expm1f(v);
      v *= drop_scale((uint32_t)idx, k0, k1);
    }
    out[idx] = v;
  }
}

// ---------------- Launch ----------------
extern "C" void kernel_launch(void* const* d_in, const int* in_sizes, int n_in,
                              void* d_out, int out_size, void* d_ws, size_t ws_size,
                              hipStream_t stream) {
  const float* x  = (const float*)d_in[0];
  const int*   ei = (const int*)d_in[1];
  const float* W1 = (const float*)d_in[2];
  const float* b1 = (const float*)d_in[3];
  const float* W2 = (const float*)d_in[4];
  const float* b2 = (const float*)d_in[5];
  const float* W3 = (const float*)d_in[6];
  const float* b3 = (const float*)d_in[7];
  float* out = (float*)d_out;

  char* ws = (char*)d_ws;
  size_t off = 0;
  auto alloc = [&](size_t bytes) -> char* {
    char* p = ws + off;
    off += (bytes + 255) & ~(size_t)255;
    return p;
  };
  int*   flag   = (int*)alloc(256);
  int*   deg    = (int*)alloc((size_t)N_NODES * 4);
  int*   cursor = (int*)alloc((size_t)N_NODES * 4);
  float* dis    = (float*)alloc((size_t)N_NODES * 4);
  int*   rptr   = (int*)alloc((size_t)(N_NODES + 1) * 4);
  int*   row32  = (int*)alloc((size_t)N_EDGES * 4);
  int*   col32  = (int*)alloc((size_t)N_EDGES * 4);
  int*   erow   = (int*)alloc((size_t)N_EDGES * 4);
  float* enorm  = (float*)alloc((size_t)N_EDGES * 4);
  float* R0 = (float*)alloc((size_t)N_NODES * 128 * 4);
  float* R1 = (float*)alloc((size_t)N_NODES * 128 * 4);
  float* R2 = (float*)alloc((size_t)N_NODES * 128 * 4);
  float* R3 = (float*)alloc((size_t)N_NODES * 128 * 4);

  hipMemsetAsync(flag, 0, 256, stream);
  hipMemsetAsync(deg, 0, (size_t)N_NODES * 4, stream);
  hipMemsetAsync(cursor, 0, (size_t)N_NODES * 4, stream);

  detect_kernel<<<8, 256, 0, stream>>>(ei, flag);
  convert_kernel<<<(N_EDGES + 255) / 256, 256, 0, stream>>>(ei, flag, row32, col32);
  deg_kernel<<<(N_EDGES + 255) / 256, 256, 0, stream>>>(col32, deg);
  dis_kernel<<<(N_NODES + 255) / 256, 256, 0, stream>>>(deg, dis);
  scan_kernel<<<1, 1024, 0, stream>>>(deg, rptr, N_NODES);
  fill_kernel<<<(N_EDGES + 255) / 256, 256, 0, stream>>>(row32, col32, dis, rptr,
                                                         cursor, erow, enorm);

  // JAX partitionable split of key(42)=(0,42): subkey_i = threefry(key; 0, i)
  uint32_t d10, d11, d20, d21;
  threefry2x32(0u, 42u, 0u, 0u, d10, d11);  // dk1
  threefry2x32(0u, 42u, 0u, 1u, d20, d21);  // dk2

  const int MMBLK = (N_NODES + 31) / 32;
  const int PB4   = (N_NODES + 3) / 4;     // 4 nodes/block (D=128, D=64)
  const int PB16  = (N_NODES + 15) / 16;   // 16 nodes/block (D=16)

  // ---- Layer 1 (128 -> 128): out = A(A(A y3 + y2) + y1) + y0 ; then dropout1
  matmul4_kernel<128, 128><<<MMBLK, 256, 0, stream>>>(x, W1, b1, R0, R1, R2, R3);
  prop_kernel<128, 0><<<PB4, 256, 0, stream>>>(R3, R2, R2, rptr, erow, enorm, 0, 0);
  prop_kernel<128, 0><<<PB4, 256, 0, stream>>>(R2, R1, R1, rptr, erow, enorm, 0, 0);
  prop_kernel<128, 1><<<PB4, 256, 0, stream>>>(R1, R0, R0, rptr, erow, enorm, d10, d11);
  // ---- Layer 2 (128 -> 64): h = R0; epilogue: elu + dropout2
  float* y0 = R1;
  float* y1 = R1 + (size_t)N_NODES * 64;
  float* y2 = R2;
  float* y3 = R2 + (size_t)N_NODES * 64;
  matmul4_kernel<128, 64><<<MMBLK, 256, 0, stream>>>(R0, W2, b2, y0, y1, y2, y3);
  prop_kernel<64, 0><<<PB4, 256, 0, stream>>>(y3, y2, y2, rptr, erow, enorm, 0, 0);
  prop_kernel<64, 0><<<PB4, 256, 0, stream>>>(y2, y1, y1, rptr, erow, enorm, 0, 0);
  prop_kernel<64, 2><<<PB4, 256, 0, stream>>>(y1, y0, y0, rptr, erow, enorm, d20, d21);
  // ---- Layer 3 (64 -> 16): h = y0 (R1); final hop writes d_out
  float* z0 = R2;
  float* z1 = R2 + (size_t)N_NODES * 16;
  float* z2 = R2 + (size_t)N_NODES * 32;
  float* z3 = R2 + (size_t)N_NODES * 48;
  matmul4_kernel<64, 16><<<MMBLK, 256, 0, stream>>>(y0, W3, b3, z0, z1, z2, z3);
  prop_kernel<16, 0><<<PB16, 256, 0, stream>>>(z3, z2, z2, rptr, erow, enorm, 0, 0);
  prop_kernel<16, 0><<<PB16, 256, 0, stream>>>(z2, z1, z1, rptr, erow, enorm, 0, 0);
  prop_kernel<16, 0><<<PB16, 256, 0, stream>>>(z1, z0, out, rptr, erow, enorm, 0, 0);

  (void)in_sizes; (void)n_in; (void)out_size; (void)ws_size;
}

// Round 3
// 1596.882 us; speedup vs baseline: 1.8163x; 1.8163x over previous
//
#include <hip/hip_runtime.h>
#include <stdint.h>
#include <math.h>

#define N_NODES 100000
#define N_EDGES 1600000

typedef __bf16 bf16_t;
typedef __attribute__((ext_vector_type(8))) __bf16 bf16x8;
typedef __attribute__((ext_vector_type(4))) float f32x4;

__device__ __forceinline__ f32x4 mfma16(bf16x8 a, bf16x8 b, f32x4 c) {
  return __builtin_amdgcn_mfma_f32_16x16x32_bf16(a, b, c, 0, 0, 0);
}

// ---------------- Threefry-2x32 (JAX-compatible) ----------------
__device__ __host__ __forceinline__ uint32_t rotl32(uint32_t v, int d) {
  return (v << d) | (v >> (32 - d));
}

__device__ __host__ __forceinline__ void threefry2x32(uint32_t k0, uint32_t k1,
                                                      uint32_t x0, uint32_t x1,
                                                      uint32_t& o0, uint32_t& o1) {
  uint32_t ks0 = k0, ks1 = k1, ks2 = k0 ^ k1 ^ 0x1BD11BDAu;
  x0 += ks0; x1 += ks1;
#define TF_R(r) { x0 += x1; x1 = rotl32(x1, r); x1 ^= x0; }
  TF_R(13) TF_R(15) TF_R(26) TF_R(6)
  x0 += ks1; x1 += ks2 + 1u;
  TF_R(17) TF_R(29) TF_R(16) TF_R(24)
  x0 += ks2; x1 += ks0 + 2u;
  TF_R(13) TF_R(15) TF_R(26) TF_R(6)
  x0 += ks0; x1 += ks1 + 3u;
  TF_R(17) TF_R(29) TF_R(16) TF_R(24)
  x0 += ks1; x1 += ks2 + 4u;
  TF_R(13) TF_R(15) TF_R(26) TF_R(6)
  x0 += ks2; x1 += ks0 + 5u;
#undef TF_R
  o0 = x0; o1 = x1;
}

// Partitionable-threefry dropout (JAX default): bits = o0^o1 of tf(key; 0, idx)
__device__ __forceinline__ float drop_scale(uint32_t idx, uint32_t k0, uint32_t k1) {
  uint32_t o0, o1;
  threefry2x32(k0, k1, 0u, idx, o0, o1);
  uint32_t bits = o0 ^ o1;
  float u = __uint_as_float((bits >> 9) | 0x3f800000u) - 1.0f;
  return (u < 0.5f) ? 2.0f : 0.0f;
}

// ---------------- Edge dtype detect + canonicalize ----------------
__global__ __launch_bounds__(256) void detect_kernel(const int* __restrict__ ei,
                                                     int* __restrict__ found_nonzero) {
  int idx = blockIdx.x * 256 + threadIdx.x;  // 0..2047
  size_t j = (size_t)idx * 781;              // < 1.6M
  if (ei[2 * j + 1] != 0) atomicOr(found_nonzero, 1);
}

__global__ __launch_bounds__(256) void convert_kernel(const int* __restrict__ ei,
                                                      const int* __restrict__ found_nonzero,
                                                      int* __restrict__ row32,
                                                      int* __restrict__ col32) {
  int e = blockIdx.x * 256 + threadIdx.x;
  if (e >= N_EDGES) return;
  if (*found_nonzero) {  // int32 layout
    row32[e] = ei[e];
    col32[e] = ei[N_EDGES + e];
  } else {               // int64 layout: take low words
    row32[e] = ei[2 * (size_t)e];
    col32[e] = ei[2 * ((size_t)N_EDGES + (size_t)e)];
  }
}

// ---------------- Graph preprocessing ----------------
__global__ __launch_bounds__(256) void deg_kernel(const int* __restrict__ col,
                                                  int* __restrict__ deg) {
  int e = blockIdx.x * 256 + threadIdx.x;
  if (e < N_EDGES) atomicAdd(&deg[col[e]], 1);
}

__global__ __launch_bounds__(256) void dis_kernel(const int* __restrict__ deg,
                                                  float* __restrict__ dis) {
  int n = blockIdx.x * 256 + threadIdx.x;
  if (n < N_NODES) {
    int d = deg[n];
    dis[n] = (d > 0) ? (1.0f / sqrtf((float)d)) : 0.0f;
  }
}

// 3-phase parallel exclusive scan of deg -> rptr (N_NODES+1 entries)
#define SCAN_NB 391  // ceil(100000/256)
__global__ __launch_bounds__(256) void bsum_kernel(const int* __restrict__ deg,
                                                   int* __restrict__ bsum) {
  __shared__ int sh[256];
  int i = blockIdx.x * 256 + threadIdx.x;
  sh[threadIdx.x] = (i < N_NODES) ? deg[i] : 0;
  __syncthreads();
  for (int ofs = 128; ofs > 0; ofs >>= 1) {
    if (threadIdx.x < ofs) sh[threadIdx.x] += sh[threadIdx.x + ofs];
    __syncthreads();
  }
  if (threadIdx.x == 0) bsum[blockIdx.x] = sh[0];
}

__global__ __launch_bounds__(512) void bscan_kernel(const int* __restrict__ bsum,
                                                    int* __restrict__ boffs) {
  __shared__ int sh[512];
  int t = threadIdx.x;
  int v = (t < SCAN_NB) ? bsum[t] : 0;
  sh[t] = v;
  __syncthreads();
  for (int ofs = 1; ofs < 512; ofs <<= 1) {
    int u = (t >= ofs) ? sh[t - ofs] : 0;
    __syncthreads();
    sh[t] += u;
    __syncthreads();
  }
  if (t < SCAN_NB) boffs[t] = sh[t] - v;  // exclusive
  if (t == 0) boffs[SCAN_NB] = sh[SCAN_NB - 1];
}

__global__ __launch_bounds__(256) void rptr_kernel(const int* __restrict__ deg,
                                                   const int* __restrict__ boffs,
                                                   int* __restrict__ rptr) {
  __shared__ int sh[256];
  int i = blockIdx.x * 256 + threadIdx.x;
  int v = (i < N_NODES) ? deg[i] : 0;
  sh[threadIdx.x] = v;
  __syncthreads();
  for (int ofs = 1; ofs < 256; ofs <<= 1) {
    int u = (threadIdx.x >= ofs) ? sh[threadIdx.x - ofs] : 0;
    __syncthreads();
    sh[threadIdx.x] += u;
    __syncthreads();
  }
  if (i <= N_NODES) rptr[i] = boffs[blockIdx.x] + sh[threadIdx.x] - v;
}

__global__ __launch_bounds__(256) void fill_kernel(const int* __restrict__ row,
                                                   const int* __restrict__ col,
                                                   const float* __restrict__ dis,
                                                   const int* __restrict__ rptr,
                                                   int* cursor,
                                                   int* __restrict__ erow,
                                                   float* __restrict__ enorm) {
  int e = blockIdx.x * 256 + threadIdx.x;
  if (e < N_EDGES) {
    int c = col[e], r = row[e];
    int p = atomicAdd(&cursor[c], 1);
    int idx = rptr[c] + p;
    erow[idx] = r;
    enorm[idx] = dis[r] * dis[c];
  }
}

// ---------------- MFMA matmul: y_k = h @ W_k^T (+bias into y0) ----------------
// Split precision: A = hi+lo bf16 (exact), W = bf16 (RNE). D = Ahi*W + Alo*W.
// Block tile 64(M) x 64(N), 4 waves in 2x2; wave tile 32x32 = 2x2 mfma 16x16x32.
template <int DIN, int LOG_DOUT>
__global__ __launch_bounds__(256) void matmul_mfma_kernel(
    const float* __restrict__ h, const float* __restrict__ W,
    const float* __restrict__ bias,
    float* __restrict__ y0, float* __restrict__ y1,
    float* __restrict__ y2, float* __restrict__ y3) {
  constexpr int LDK = DIN + 8;  // +16B pad -> 2-way-only bank aliasing (free)
  constexpr int DOUT = 1 << LOG_DOUT;
  __shared__ bf16_t sAhi[64 * LDK];
  __shared__ bf16_t sAlo[64 * LDK];
  __shared__ bf16_t sB[64 * LDK];
  const int m0 = blockIdx.x * 64;
  const int n0 = blockIdx.y * 64;
  const int tid = threadIdx.x;

  // Stage A (h rows m0..m0+63) as hi/lo bf16, W rows n0..n0+63 as bf16.
  constexpr int NLOAD = 64 * DIN / 4 / 256;
  union U4 { bf16_t b[4]; uint2 u; };
  for (int it = 0; it < NLOAD; ++it) {
    int idx = tid + it * 256;
    int r = idx / (DIN / 4);
    int cc = (idx % (DIN / 4)) * 4;
    int gm = m0 + r;
    float4 v = (gm < N_NODES) ? ((const float4*)h)[((size_t)gm * DIN + cc) >> 2]
                              : make_float4(0.f, 0.f, 0.f, 0.f);
    U4 hi, lo;
    hi.b[0] = (bf16_t)v.x; lo.b[0] = (bf16_t)(v.x - (float)hi.b[0]);
    hi.b[1] = (bf16_t)v.y; lo.b[1] = (bf16_t)(v.y - (float)hi.b[1]);
    hi.b[2] = (bf16_t)v.z; lo.b[2] = (bf16_t)(v.z - (float)hi.b[2]);
    hi.b[3] = (bf16_t)v.w; lo.b[3] = (bf16_t)(v.w - (float)hi.b[3]);
    *(uint2*)&sAhi[r * LDK + cc] = hi.u;
    *(uint2*)&sAlo[r * LDK + cc] = lo.u;
  }
  for (int it = 0; it < NLOAD; ++it) {
    int idx = tid + it * 256;
    int r = idx / (DIN / 4);
    int cc = (idx % (DIN / 4)) * 4;
    float4 v = ((const float4*)W)[((size_t)(n0 + r) * DIN + cc) >> 2];
    U4 wb;
    wb.b[0] = (bf16_t)v.x; wb.b[1] = (bf16_t)v.y;
    wb.b[2] = (bf16_t)v.z; wb.b[3] = (bf16_t)v.w;
    *(uint2*)&sB[r * LDK + cc] = wb.u;
  }
  __syncthreads();

  const int w = tid >> 6, lane = tid & 63;
  const int wm = w & 1, wn = w >> 1;
  const int quad = lane >> 4, lr = lane & 15;

  f32x4 acc[2][2] = {};
#pragma unroll
  for (int kt = 0; kt < DIN; kt += 32) {
    int koff = kt + quad * 8;
    bf16x8 ahi[2], alo[2], bfr[2];
#pragma unroll
    for (int mt = 0; mt < 2; ++mt) {
      int rowa = wm * 32 + mt * 16 + lr;
      ahi[mt] = *(const bf16x8*)&sAhi[rowa * LDK + koff];
      alo[mt] = *(const bf16x8*)&sAlo[rowa * LDK + koff];
    }
#pragma unroll
    for (int nt = 0; nt < 2; ++nt) {
      int rowb = wn * 32 + nt * 16 + lr;
      bfr[nt] = *(const bf16x8*)&sB[rowb * LDK + koff];
    }
#pragma unroll
    for (int mt = 0; mt < 2; ++mt)
#pragma unroll
      for (int nt = 0; nt < 2; ++nt) {
        acc[mt][nt] = mfma16(ahi[mt], bfr[nt], acc[mt][nt]);
        acc[mt][nt] = mfma16(alo[mt], bfr[nt], acc[mt][nt]);
      }
  }

  // D[row=quad*4+r][col=lr]; n_global -> (k = n>>LOG_DOUT, o = n&(DOUT-1))
#pragma unroll
  for (int mt = 0; mt < 2; ++mt)
#pragma unroll
    for (int nt = 0; nt < 2; ++nt) {
      int ng = n0 + wn * 32 + nt * 16 + lr;
      int k = ng >> LOG_DOUT;
      int o = ng & (DOUT - 1);
      float* yk = (k == 0) ? y0 : (k == 1) ? y1 : (k == 2) ? y2 : y3;
      float badd = (k == 0) ? bias[o] : 0.f;
#pragma unroll
      for (int r = 0; r < 4; ++r) {
        int m = m0 + wm * 32 + mt * 16 + quad * 4 + r;
        if (m < N_NODES) yk[(size_t)m * DOUT + o] = acc[mt][nt][r] + badd;
      }
    }
}

// ---------------- Propagation: out[c] = sum_e norm*z[row_e] + add[c] ----------
// EPI: 0 = none, 1 = dropout(key1), 2 = elu then dropout(key2)
template <int D, int EPI>
__global__ __launch_bounds__(256) void prop_kernel(
    const float* __restrict__ z, const float* addb, float* out,
    const int* __restrict__ rptr, const int* __restrict__ erow,
    const float* __restrict__ enorm,
    uint32_t k0, uint32_t k1) {
  constexpr int LPN = (D >= 64) ? 64 : D;  // lanes per node
  constexpr int VEC = (D == 128) ? 2 : 1;  // floats per lane
  constexpr int NPB = 256 / LPN;           // nodes per block
  int lane = threadIdx.x % LPN;
  int nsub = threadIdx.x / LPN;
  int c = blockIdx.x * NPB + nsub;
  if (c >= N_NODES) return;
  int e0 = rptr[c], e1 = rptr[c + 1];
  float acc0 = 0.f, acc1 = 0.f;
  if (VEC == 2) {
    const float2* zz = (const float2*)z;
    for (int e = e0; e < e1; ++e) {
      int r = erow[e];
      float wv = enorm[e];
      float2 v = zz[(size_t)r * 64 + lane];
      acc0 = fmaf(wv, v.x, acc0);
      acc1 = fmaf(wv, v.y, acc1);
    }
    size_t base = (size_t)c * 128 + 2 * lane;
    float2 a = ((const float2*)addb)[(size_t)c * 64 + lane];
    float v0 = acc0 + a.x, v1 = acc1 + a.y;
    if (EPI == 1) {
      v0 *= drop_scale((uint32_t)base, k0, k1);
      v1 *= drop_scale((uint32_t)base + 1, k0, k1);
    }
    ((float2*)out)[(size_t)c * 64 + lane] = make_float2(v0, v1);
  } else {
    for (int e = e0; e < e1; ++e) {
      int r = erow[e];
      float wv = enorm[e];
      acc0 = fmaf(wv, z[(size_t)r * D + lane], acc0);
    }
    size_t idx = (size_t)c * D + lane;
    float v = acc0 + addb[idx];
    if (EPI == 2) {
      v = (v > 0.f) ? v : expm1f(v);
      v *= drop_scale((uint32_t)idx, k0, k1);
    }
    out[idx] = v;
  }
}

// ---------------- Launch ----------------
extern "C" void kernel_launch(void* const* d_in, const int* in_sizes, int n_in,
                              void* d_out, int out_size, void* d_ws, size_t ws_size,
                              hipStream_t stream) {
  const float* x  = (const float*)d_in[0];
  const int*   ei = (const int*)d_in[1];
  const float* W1 = (const float*)d_in[2];
  const float* b1 = (const float*)d_in[3];
  const float* W2 = (const float*)d_in[4];
  const float* b2 = (const float*)d_in[5];
  const float* W3 = (const float*)d_in[6];
  const float* b3 = (const float*)d_in[7];
  float* out = (float*)d_out;

  char* ws = (char*)d_ws;
  size_t off = 0;
  auto alloc = [&](size_t bytes) -> char* {
    char* p = ws + off;
    off += (bytes + 255) & ~(size_t)255;
    return p;
  };
  int*   flag   = (int*)alloc(256);
  int*   deg    = (int*)alloc((size_t)N_NODES * 4);
  int*   cursor = (int*)alloc((size_t)N_NODES * 4);
  float* dis    = (float*)alloc((size_t)N_NODES * 4);
  int*   rptr   = (int*)alloc((size_t)(N_NODES + 1) * 4);
  int*   bsum   = (int*)alloc((size_t)(SCAN_NB + 1) * 4);
  int*   boffs  = (int*)alloc((size_t)(SCAN_NB + 1) * 4);
  int*   row32  = (int*)alloc((size_t)N_EDGES * 4);
  int*   col32  = (int*)alloc((size_t)N_EDGES * 4);
  int*   erow   = (int*)alloc((size_t)N_EDGES * 4);
  float* enorm  = (float*)alloc((size_t)N_EDGES * 4);
  float* R0 = (float*)alloc((size_t)N_NODES * 128 * 4);
  float* R1 = (float*)alloc((size_t)N_NODES * 128 * 4);
  float* R2 = (float*)alloc((size_t)N_NODES * 128 * 4);
  float* R3 = (float*)alloc((size_t)N_NODES * 128 * 4);

  hipMemsetAsync(flag, 0, 256, stream);
  hipMemsetAsync(deg, 0, (size_t)N_NODES * 4, stream);
  hipMemsetAsync(cursor, 0, (size_t)N_NODES * 4, stream);

  detect_kernel<<<8, 256, 0, stream>>>(ei, flag);
  convert_kernel<<<(N_EDGES + 255) / 256, 256, 0, stream>>>(ei, flag, row32, col32);
  deg_kernel<<<(N_EDGES + 255) / 256, 256, 0, stream>>>(col32, deg);
  dis_kernel<<<(N_NODES + 255) / 256, 256, 0, stream>>>(deg, dis);
  bsum_kernel<<<SCAN_NB, 256, 0, stream>>>(deg, bsum);
  bscan_kernel<<<1, 512, 0, stream>>>(bsum, boffs);
  rptr_kernel<<<SCAN_NB, 256, 0, stream>>>(deg, boffs, rptr);
  fill_kernel<<<(N_EDGES + 255) / 256, 256, 0, stream>>>(row32, col32, dis, rptr,
                                                         cursor, erow, enorm);

  // JAX partitionable split of key(42)=(0,42): subkey_i = threefry(key; 0, i)
  uint32_t d10, d11, d20, d21;
  threefry2x32(0u, 42u, 0u, 0u, d10, d11);  // dk1
  threefry2x32(0u, 42u, 0u, 1u, d20, d21);  // dk2

  const int MB = (N_NODES + 63) / 64;      // 1563
  const int PB4  = (N_NODES + 3) / 4;
  const int PB16 = (N_NODES + 15) / 16;

  // ---- Layer 1 (128 -> 128): Horner: out = A(A(A y3 + y2) + y1) + y0 ; dropout1
  matmul_mfma_kernel<128, 7><<<dim3(MB, 8), 256, 0, stream>>>(x, W1, b1, R0, R1, R2, R3);
  prop_kernel<128, 0><<<PB4, 256, 0, stream>>>(R3, R2, R2, rptr, erow, enorm, 0, 0);
  prop_kernel<128, 0><<<PB4, 256, 0, stream>>>(R2, R1, R1, rptr, erow, enorm, 0, 0);
  prop_kernel<128, 1><<<PB4, 256, 0, stream>>>(R1, R0, R0, rptr, erow, enorm, d10, d11);
  // ---- Layer 2 (128 -> 64): h = R0; epilogue: elu + dropout2
  float* y0 = R1;
  float* y1 = R1 + (size_t)N_NODES * 64;
  float* y2 = R2;
  float* y3 = R2 + (size_t)N_NODES * 64;
  matmul_mfma_kernel<128, 6><<<dim3(MB, 4), 256, 0, stream>>>(R0, W2, b2, y0, y1, y2, y3);
  prop_kernel<64, 0><<<PB4, 256, 0, stream>>>(y3, y2, y2, rptr, erow, enorm, 0, 0);
  prop_kernel<64, 0><<<PB4, 256, 0, stream>>>(y2, y1, y1, rptr, erow, enorm, 0, 0);
  prop_kernel<64, 2><<<PB4, 256, 0, stream>>>(y1, y0, y0, rptr, erow, enorm, d20, d21);
  // ---- Layer 3 (64 -> 16): h = y0 (R1); final hop writes d_out
  float* z0 = R2;
  float* z1 = R2 + (size_t)N_NODES * 16;
  float* z2 = R2 + (size_t)N_NODES * 32;
  float* z3 = R2 + (size_t)N_NODES * 48;
  matmul_mfma_kernel<64, 4><<<dim3(MB, 1), 256, 0, stream>>>(y0, W3, b3, z0, z1, z2, z3);
  prop_kernel<16, 0><<<PB16, 256, 0, stream>>>(z3, z2, z2, rptr, erow, enorm, 0, 0);
  prop_kernel<16, 0><<<PB16, 256, 0, stream>>>(z2, z1, z1, rptr, erow, enorm, 0, 0);
  prop_kernel<16, 0><<<PB16, 256, 0, stream>>>(z1, z0, out, rptr, erow, enorm, 0, 0);

  (void)in_sizes; (void)n_in; (void)out_size; (void)ws_size;
}

// Round 4
// 956.826 us; speedup vs baseline: 3.0312x; 1.6689x over previous
//
#include <hip/hip_runtime.h>
#include <stdint.h>
#include <math.h>

#define N_NODES 100000
#define N_EDGES 1600000

typedef __bf16 bf16_t;
typedef __attribute__((ext_vector_type(2))) __bf16 bf16x2;
typedef __attribute__((ext_vector_type(8))) __bf16 bf16x8;
typedef __attribute__((ext_vector_type(4))) float f32x4;

__device__ __forceinline__ f32x4 mfma16(bf16x8 a, bf16x8 b, f32x4 c) {
  return __builtin_amdgcn_mfma_f32_16x16x32_bf16(a, b, c, 0, 0, 0);
}

// ---------------- Threefry-2x32 (JAX-compatible) ----------------
__device__ __host__ __forceinline__ uint32_t rotl32(uint32_t v, int d) {
  return (v << d) | (v >> (32 - d));
}

__device__ __host__ __forceinline__ void threefry2x32(uint32_t k0, uint32_t k1,
                                                      uint32_t x0, uint32_t x1,
                                                      uint32_t& o0, uint32_t& o1) {
  uint32_t ks0 = k0, ks1 = k1, ks2 = k0 ^ k1 ^ 0x1BD11BDAu;
  x0 += ks0; x1 += ks1;
#define TF_R(r) { x0 += x1; x1 = rotl32(x1, r); x1 ^= x0; }
  TF_R(13) TF_R(15) TF_R(26) TF_R(6)
  x0 += ks1; x1 += ks2 + 1u;
  TF_R(17) TF_R(29) TF_R(16) TF_R(24)
  x0 += ks2; x1 += ks0 + 2u;
  TF_R(13) TF_R(15) TF_R(26) TF_R(6)
  x0 += ks0; x1 += ks1 + 3u;
  TF_R(17) TF_R(29) TF_R(16) TF_R(24)
  x0 += ks1; x1 += ks2 + 4u;
  TF_R(13) TF_R(15) TF_R(26) TF_R(6)
  x0 += ks2; x1 += ks0 + 5u;
#undef TF_R
  o0 = x0; o1 = x1;
}

// Partitionable-threefry dropout (JAX default): bits = o0^o1 of tf(key; 0, idx)
__device__ __forceinline__ float drop_scale(uint32_t idx, uint32_t k0, uint32_t k1) {
  uint32_t o0, o1;
  threefry2x32(k0, k1, 0u, idx, o0, o1);
  uint32_t bits = o0 ^ o1;
  float u = __uint_as_float((bits >> 9) | 0x3f800000u) - 1.0f;
  return (u < 0.5f) ? 2.0f : 0.0f;
}

// ---------------- Edge dtype detect + canonicalize ----------------
__global__ __launch_bounds__(256) void detect_kernel(const int* __restrict__ ei,
                                                     int* __restrict__ found_nonzero) {
  int idx = blockIdx.x * 256 + threadIdx.x;  // 0..2047
  size_t j = (size_t)idx * 781;              // < 1.6M
  if (ei[2 * j + 1] != 0) atomicOr(found_nonzero, 1);
}

__global__ __launch_bounds__(256) void convert_kernel(const int* __restrict__ ei,
                                                      const int* __restrict__ found_nonzero,
                                                      int* __restrict__ row32,
                                                      int* __restrict__ col32) {
  int e = blockIdx.x * 256 + threadIdx.x;
  if (e >= N_EDGES) return;
  if (*found_nonzero) {  // int32 layout
    row32[e] = ei[e];
    col32[e] = ei[N_EDGES + e];
  } else {               // int64 layout: take low words
    row32[e] = ei[2 * (size_t)e];
    col32[e] = ei[2 * ((size_t)N_EDGES + (size_t)e)];
  }
}

// ---------------- Graph preprocessing ----------------
__global__ __launch_bounds__(256) void deg_kernel(const int* __restrict__ col,
                                                  int* __restrict__ deg) {
  int e = blockIdx.x * 256 + threadIdx.x;
  if (e < N_EDGES) atomicAdd(&deg[col[e]], 1);
}

__global__ __launch_bounds__(256) void dis_kernel(const int* __restrict__ deg,
                                                  float* __restrict__ dis) {
  int n = blockIdx.x * 256 + threadIdx.x;
  if (n < N_NODES) {
    int d = deg[n];
    dis[n] = (d > 0) ? (1.0f / sqrtf((float)d)) : 0.0f;
  }
}

// 3-phase parallel exclusive scan of deg -> rptr (N_NODES+1 entries)
#define SCAN_NB 391  // ceil(100000/256)
__global__ __launch_bounds__(256) void bsum_kernel(const int* __restrict__ deg,
                                                   int* __restrict__ bsum) {
  __shared__ int sh[256];
  int i = blockIdx.x * 256 + threadIdx.x;
  sh[threadIdx.x] = (i < N_NODES) ? deg[i] : 0;
  __syncthreads();
  for (int ofs = 128; ofs > 0; ofs >>= 1) {
    if (threadIdx.x < ofs) sh[threadIdx.x] += sh[threadIdx.x + ofs];
    __syncthreads();
  }
  if (threadIdx.x == 0) bsum[blockIdx.x] = sh[0];
}

__global__ __launch_bounds__(512) void bscan_kernel(const int* __restrict__ bsum,
                                                    int* __restrict__ boffs) {
  __shared__ int sh[512];
  int t = threadIdx.x;
  int v = (t < SCAN_NB) ? bsum[t] : 0;
  sh[t] = v;
  __syncthreads();
  for (int ofs = 1; ofs < 512; ofs <<= 1) {
    int u = (t >= ofs) ? sh[t - ofs] : 0;
    __syncthreads();
    sh[t] += u;
    __syncthreads();
  }
  if (t < SCAN_NB) boffs[t] = sh[t] - v;  // exclusive
  if (t == 0) boffs[SCAN_NB] = sh[SCAN_NB - 1];
}

__global__ __launch_bounds__(256) void rptr_kernel(const int* __restrict__ deg,
                                                   const int* __restrict__ boffs,
                                                   int* __restrict__ rptr) {
  __shared__ int sh[256];
  int i = blockIdx.x * 256 + threadIdx.x;
  int v = (i < N_NODES) ? deg[i] : 0;
  sh[threadIdx.x] = v;
  __syncthreads();
  for (int ofs = 1; ofs < 256; ofs <<= 1) {
    int u = (threadIdx.x >= ofs) ? sh[threadIdx.x - ofs] : 0;
    __syncthreads();
    sh[threadIdx.x] += u;
    __syncthreads();
  }
  if (i <= N_NODES) rptr[i] = boffs[blockIdx.x] + sh[threadIdx.x] - v;
}

__global__ __launch_bounds__(256) void fill_kernel(const int* __restrict__ row,
                                                   const int* __restrict__ col,
                                                   const float* __restrict__ dis,
                                                   const int* __restrict__ rptr,
                                                   int* cursor,
                                                   int* __restrict__ erow,
                                                   float* __restrict__ enorm) {
  int e = blockIdx.x * 256 + threadIdx.x;
  if (e < N_EDGES) {
    int c = col[e], r = row[e];
    int p = atomicAdd(&cursor[c], 1);
    int idx = rptr[c] + p;
    erow[idx] = r;
    enorm[idx] = dis[r] * dis[c];
  }
}

// ---------------- MFMA matmul: y_k = h @ W_k^T (+bias into y0) ----------------
// Split precision: A = hi+lo bf16 (exact), W = bf16 (RNE). D = Ahi*W + Alo*W.
// Block tile 64(M) x 64(N), 4 waves 2x2; wave tile 32x32 = 2x2 mfma 16x16x32.
// Y3B: emit y3 as bf16 (it is only ever consumed as a prop z-operand).
template <int DIN, int LOG_DOUT, bool Y3B>
__global__ __launch_bounds__(256) void matmul_mfma_kernel(
    const float* __restrict__ h, const float* __restrict__ W,
    const float* __restrict__ bias,
    float* __restrict__ y0, float* __restrict__ y1,
    float* __restrict__ y2, void* __restrict__ y3) {
  constexpr int LDK = DIN + 8;  // +16B pad -> 2-way-only bank aliasing (free)
  constexpr int DOUT = 1 << LOG_DOUT;
  __shared__ bf16_t sAhi[64 * LDK];
  __shared__ bf16_t sAlo[64 * LDK];
  __shared__ bf16_t sB[64 * LDK];
  const int m0 = blockIdx.x * 64;
  const int n0 = blockIdx.y * 64;
  const int tid = threadIdx.x;

  constexpr int NLOAD = 64 * DIN / 4 / 256;
  union U4 { bf16_t b[4]; uint2 u; };
  for (int it = 0; it < NLOAD; ++it) {
    int idx = tid + it * 256;
    int r = idx / (DIN / 4);
    int cc = (idx % (DIN / 4)) * 4;
    int gm = m0 + r;
    float4 v = (gm < N_NODES) ? ((const float4*)h)[((size_t)gm * DIN + cc) >> 2]
                              : make_float4(0.f, 0.f, 0.f, 0.f);
    U4 hi, lo;
    hi.b[0] = (bf16_t)v.x; lo.b[0] = (bf16_t)(v.x - (float)hi.b[0]);
    hi.b[1] = (bf16_t)v.y; lo.b[1] = (bf16_t)(v.y - (float)hi.b[1]);
    hi.b[2] = (bf16_t)v.z; lo.b[2] = (bf16_t)(v.z - (float)hi.b[2]);
    hi.b[3] = (bf16_t)v.w; lo.b[3] = (bf16_t)(v.w - (float)hi.b[3]);
    *(uint2*)&sAhi[r * LDK + cc] = hi.u;
    *(uint2*)&sAlo[r * LDK + cc] = lo.u;
  }
  for (int it = 0; it < NLOAD; ++it) {
    int idx = tid + it * 256;
    int r = idx / (DIN / 4);
    int cc = (idx % (DIN / 4)) * 4;
    float4 v = ((const float4*)W)[((size_t)(n0 + r) * DIN + cc) >> 2];
    U4 wb;
    wb.b[0] = (bf16_t)v.x; wb.b[1] = (bf16_t)v.y;
    wb.b[2] = (bf16_t)v.z; wb.b[3] = (bf16_t)v.w;
    *(uint2*)&sB[r * LDK + cc] = wb.u;
  }
  __syncthreads();

  const int w = tid >> 6, lane = tid & 63;
  const int wm = w & 1, wn = w >> 1;
  const int quad = lane >> 4, lr = lane & 15;

  f32x4 acc[2][2] = {};
#pragma unroll
  for (int kt = 0; kt < DIN; kt += 32) {
    int koff = kt + quad * 8;
    bf16x8 ahi[2], alo[2], bfr[2];
#pragma unroll
    for (int mt = 0; mt < 2; ++mt) {
      int rowa = wm * 32 + mt * 16 + lr;
      ahi[mt] = *(const bf16x8*)&sAhi[rowa * LDK + koff];
      alo[mt] = *(const bf16x8*)&sAlo[rowa * LDK + koff];
    }
#pragma unroll
    for (int nt = 0; nt < 2; ++nt) {
      int rowb = wn * 32 + nt * 16 + lr;
      bfr[nt] = *(const bf16x8*)&sB[rowb * LDK + koff];
    }
#pragma unroll
    for (int mt = 0; mt < 2; ++mt)
#pragma unroll
      for (int nt = 0; nt < 2; ++nt) {
        acc[mt][nt] = mfma16(ahi[mt], bfr[nt], acc[mt][nt]);
        acc[mt][nt] = mfma16(alo[mt], bfr[nt], acc[mt][nt]);
      }
  }

  // D[row=quad*4+r][col=lr]; n_global -> (k = n>>LOG_DOUT, o = n&(DOUT-1))
#pragma unroll
  for (int mt = 0; mt < 2; ++mt)
#pragma unroll
    for (int nt = 0; nt < 2; ++nt) {
      int ng = n0 + wn * 32 + nt * 16 + lr;
      int k = ng >> LOG_DOUT;
      int o = ng & (DOUT - 1);
      float* ykf = (k == 0) ? y0 : (k == 1) ? y1 : (k == 2) ? y2 : (float*)y3;
      float badd = (k == 0) ? bias[o] : 0.f;
#pragma unroll
      for (int r = 0; r < 4; ++r) {
        int m = m0 + wm * 32 + mt * 16 + quad * 4 + r;
        if (m >= N_NODES) continue;
        float val = acc[mt][nt][r] + badd;
        if (Y3B && k == 3)
          ((bf16_t*)y3)[(size_t)m * DOUT + o] = (bf16_t)val;
        else
          ykf[(size_t)m * DOUT + o] = val;
      }
    }
}

// ---------------- Propagation: out[c] = sum_e norm*z[row_e] + add[c] ----------
// 2 features per lane. ZBF: z is bf16. EMITB: also write bf16 copy of out.
// EPI: 0 = none, 1 = dropout(key1), 2 = elu then dropout(key2)
template <int D, int EPI, bool ZBF, bool EMITB>
__global__ __launch_bounds__(256) void prop_kernel(
    const void* __restrict__ zv, const float* __restrict__ addb,
    float* __restrict__ out, void* __restrict__ outb,
    const int* __restrict__ rptr, const int* __restrict__ erow,
    const float* __restrict__ enorm,
    uint32_t k0, uint32_t k1) {
  constexpr int LPN = D / 2;        // lanes per node (2 feats/lane)
  constexpr int NPB = 256 / LPN;    // nodes per block
  int lane = threadIdx.x % LPN;
  int nsub = threadIdx.x / LPN;
  int c = blockIdx.x * NPB + nsub;
  if (c >= N_NODES) return;
  int e0 = rptr[c], e1 = rptr[c + 1];
  float a0 = 0.f, a1 = 0.f;

  auto ld = [&](int r) -> float2 {
    if (ZBF) {
      bf16x2 v = ((const bf16x2*)zv)[(size_t)r * LPN + lane];
      return make_float2((float)v.x, (float)v.y);
    } else {
      return ((const float2*)zv)[(size_t)r * LPN + lane];
    }
  };

  int e = e0;
  for (; e + 3 < e1; e += 4) {
    int r0 = erow[e], r1 = erow[e + 1], r2 = erow[e + 2], r3 = erow[e + 3];
    float w0 = enorm[e], w1 = enorm[e + 1], w2 = enorm[e + 2], w3 = enorm[e + 3];
    float2 v0 = ld(r0), v1 = ld(r1), v2 = ld(r2), v3 = ld(r3);
    a0 = fmaf(w0, v0.x, a0); a1 = fmaf(w0, v0.y, a1);
    a0 = fmaf(w1, v1.x, a0); a1 = fmaf(w1, v1.y, a1);
    a0 = fmaf(w2, v2.x, a0); a1 = fmaf(w2, v2.y, a1);
    a0 = fmaf(w3, v3.x, a0); a1 = fmaf(w3, v3.y, a1);
  }
  for (; e < e1; ++e) {
    float wv = enorm[e];
    float2 v = ld(erow[e]);
    a0 = fmaf(wv, v.x, a0); a1 = fmaf(wv, v.y, a1);
  }

  size_t pidx = (size_t)c * LPN + lane;
  uint32_t fidx = (uint32_t)c * D + 2 * lane;
  float2 ad = ((const float2*)addb)[pidx];
  float o0 = a0 + ad.x, o1 = a1 + ad.y;
  if (EPI == 1) {
    o0 *= drop_scale(fidx, k0, k1);
    o1 *= drop_scale(fidx + 1, k0, k1);
  }
  if (EPI == 2) {
    o0 = (o0 > 0.f) ? o0 : expm1f(o0);
    o1 = (o1 > 0.f) ? o1 : expm1f(o1);
    o0 *= drop_scale(fidx, k0, k1);
    o1 *= drop_scale(fidx + 1, k0, k1);
  }
  ((float2*)out)[pidx] = make_float2(o0, o1);
  if (EMITB) {
    bf16x2 bv;
    bv.x = (bf16_t)o0;
    bv.y = (bf16_t)o1;
    ((bf16x2*)outb)[pidx] = bv;
  }
}

// ---------------- Launch ----------------
extern "C" void kernel_launch(void* const* d_in, const int* in_sizes, int n_in,
                              void* d_out, int out_size, void* d_ws, size_t ws_size,
                              hipStream_t stream) {
  const float* x  = (const float*)d_in[0];
  const int*   ei = (const int*)d_in[1];
  const float* W1 = (const float*)d_in[2];
  const float* b1 = (const float*)d_in[3];
  const float* W2 = (const float*)d_in[4];
  const float* b2 = (const float*)d_in[5];
  const float* W3 = (const float*)d_in[6];
  const float* b3 = (const float*)d_in[7];
  float* out = (float*)d_out;

  char* ws = (char*)d_ws;
  size_t off = 0;
  auto alloc = [&](size_t bytes) -> char* {
    char* p = ws + off;
    off += (bytes + 255) & ~(size_t)255;
    return p;
  };
  int*   flag   = (int*)alloc(256);
  int*   deg    = (int*)alloc((size_t)N_NODES * 4);
  int*   cursor = (int*)alloc((size_t)N_NODES * 4);
  float* dis    = (float*)alloc((size_t)N_NODES * 4);
  int*   rptr   = (int*)alloc((size_t)(N_NODES + 1) * 4);
  int*   bsum   = (int*)alloc((size_t)(SCAN_NB + 1) * 4);
  int*   boffs  = (int*)alloc((size_t)(SCAN_NB + 1) * 4);
  int*   row32  = (int*)alloc((size_t)N_EDGES * 4);
  int*   col32  = (int*)alloc((size_t)N_EDGES * 4);
  int*   erow   = (int*)alloc((size_t)N_EDGES * 4);
  float* enorm  = (float*)alloc((size_t)N_EDGES * 4);
  float*  R0  = (float*)alloc((size_t)N_NODES * 128 * 4);
  float*  R1  = (float*)alloc((size_t)N_NODES * 128 * 4);
  float*  R2  = (float*)alloc((size_t)N_NODES * 128 * 4);
  bf16_t* Zb0 = (bf16_t*)alloc((size_t)N_NODES * 128 * 2);
  bf16_t* Zb1 = (bf16_t*)alloc((size_t)N_NODES * 128 * 2);

  hipMemsetAsync(flag, 0, 256, stream);
  hipMemsetAsync(deg, 0, (size_t)N_NODES * 4, stream);
  hipMemsetAsync(cursor, 0, (size_t)N_NODES * 4, stream);

  detect_kernel<<<8, 256, 0, stream>>>(ei, flag);
  convert_kernel<<<(N_EDGES + 255) / 256, 256, 0, stream>>>(ei, flag, row32, col32);
  deg_kernel<<<(N_EDGES + 255) / 256, 256, 0, stream>>>(col32, deg);
  dis_kernel<<<(N_NODES + 255) / 256, 256, 0, stream>>>(deg, dis);
  bsum_kernel<<<SCAN_NB, 256, 0, stream>>>(deg, bsum);
  bscan_kernel<<<1, 512, 0, stream>>>(bsum, boffs);
  rptr_kernel<<<SCAN_NB, 256, 0, stream>>>(deg, boffs, rptr);
  fill_kernel<<<(N_EDGES + 255) / 256, 256, 0, stream>>>(row32, col32, dis, rptr,
                                                         cursor, erow, enorm);

  // JAX partitionable split of key(42)=(0,42): subkey_i = threefry(key; 0, i)
  uint32_t d10, d11, d20, d21;
  threefry2x32(0u, 42u, 0u, 0u, d10, d11);  // dk1
  threefry2x32(0u, 42u, 0u, 1u, d20, d21);  // dk2

  const int MB = (N_NODES + 63) / 64;       // 1563
  const int PB4  = (N_NODES + 3) / 4;       // D=128 (NPB=4)
  const int PB8  = (N_NODES + 7) / 8;       // D=64  (NPB=8)
  const int PB32 = (N_NODES + 31) / 32;     // D=16  (NPB=32)

  // ---- Layer 1 (128 -> 128): Horner out = A(A(A y3 + y2) + y1) + y0 ; dropout1
  matmul_mfma_kernel<128, 7, true><<<dim3(MB, 8), 256, 0, stream>>>(
      x, W1, b1, R0, R1, R2, Zb0);
  prop_kernel<128, 0, true, true><<<PB4, 256, 0, stream>>>(
      Zb0, R2, R2, Zb1, rptr, erow, enorm, 0, 0);
  prop_kernel<128, 0, true, true><<<PB4, 256, 0, stream>>>(
      Zb1, R1, R1, Zb0, rptr, erow, enorm, 0, 0);
  prop_kernel<128, 1, true, false><<<PB4, 256, 0, stream>>>(
      Zb0, R0, R0, nullptr, rptr, erow, enorm, d10, d11);
  // ---- Layer 2 (128 -> 64): h = R0; epilogue: elu + dropout2
  float* y0 = R1;
  float* y1 = R1 + (size_t)N_NODES * 64;
  float* y2 = R2;
  matmul_mfma_kernel<128, 6, true><<<dim3(MB, 4), 256, 0, stream>>>(
      R0, W2, b2, y0, y1, y2, Zb0);
  prop_kernel<64, 0, true, true><<<PB8, 256, 0, stream>>>(
      Zb0, y2, y2, Zb1, rptr, erow, enorm, 0, 0);
  prop_kernel<64, 0, true, true><<<PB8, 256, 0, stream>>>(
      Zb1, y1, y1, Zb0, rptr, erow, enorm, 0, 0);
  prop_kernel<64, 2, true, false><<<PB8, 256, 0, stream>>>(
      Zb0, y0, y0, nullptr, rptr, erow, enorm, d20, d21);
  // ---- Layer 3 (64 -> 16): h = y0 (R1); final hop writes d_out (all f32)
  float* z0 = R2;
  float* z1 = R2 + (size_t)N_NODES * 16;
  float* z2 = R2 + (size_t)N_NODES * 32;
  float* z3 = R2 + (size_t)N_NODES * 48;
  matmul_mfma_kernel<64, 4, false><<<dim3(MB, 1), 256, 0, stream>>>(
      y0, W3, b3, z0, z1, z2, z3);
  prop_kernel<16, 0, false, false><<<PB32, 256, 0, stream>>>(
      z3, z2, z2, nullptr, rptr, erow, enorm, 0, 0);
  prop_kernel<16, 0, false, false><<<PB32, 256, 0, stream>>>(
      z2, z1, z1, nullptr, rptr, erow, enorm, 0, 0);
  prop_kernel<16, 0, false, false><<<PB32, 256, 0, stream>>>(
      z1, z0, out, nullptr, rptr, erow, enorm, 0, 0);

  (void)in_sizes; (void)n_in; (void)out_size; (void)ws_size;
}

// Round 5
// 864.957 us; speedup vs baseline: 3.3532x; 1.1062x over previous
//
#include <hip/hip_runtime.h>
#include <stdint.h>
#include <math.h>

#define N_NODES 100000
#define N_EDGES 1600000

typedef __bf16 bf16_t;
typedef __attribute__((ext_vector_type(2))) __bf16 bf16x2;
typedef __attribute__((ext_vector_type(8))) __bf16 bf16x8;
typedef __attribute__((ext_vector_type(4))) float f32x4;

__device__ __forceinline__ f32x4 mfma16(bf16x8 a, bf16x8 b, f32x4 c) {
  return __builtin_amdgcn_mfma_f32_16x16x32_bf16(a, b, c, 0, 0, 0);
}

// ---------------- Threefry-2x32 (JAX-compatible) ----------------
__device__ __host__ __forceinline__ uint32_t rotl32(uint32_t v, int d) {
  return (v << d) | (v >> (32 - d));
}

__device__ __host__ __forceinline__ void threefry2x32(uint32_t k0, uint32_t k1,
                                                      uint32_t x0, uint32_t x1,
                                                      uint32_t& o0, uint32_t& o1) {
  uint32_t ks0 = k0, ks1 = k1, ks2 = k0 ^ k1 ^ 0x1BD11BDAu;
  x0 += ks0; x1 += ks1;
#define TF_R(r) { x0 += x1; x1 = rotl32(x1, r); x1 ^= x0; }
  TF_R(13) TF_R(15) TF_R(26) TF_R(6)
  x0 += ks1; x1 += ks2 + 1u;
  TF_R(17) TF_R(29) TF_R(16) TF_R(24)
  x0 += ks2; x1 += ks0 + 2u;
  TF_R(13) TF_R(15) TF_R(26) TF_R(6)
  x0 += ks0; x1 += ks1 + 3u;
  TF_R(17) TF_R(29) TF_R(16) TF_R(24)
  x0 += ks1; x1 += ks2 + 4u;
  TF_R(13) TF_R(15) TF_R(26) TF_R(6)
  x0 += ks2; x1 += ks0 + 5u;
#undef TF_R
  o0 = x0; o1 = x1;
}

// Partitionable-threefry dropout (JAX default): bits = o0^o1 of tf(key; 0, idx)
__device__ __forceinline__ float drop_scale(uint32_t idx, uint32_t k0, uint32_t k1) {
  uint32_t o0, o1;
  threefry2x32(k0, k1, 0u, idx, o0, o1);
  uint32_t bits = o0 ^ o1;
  float u = __uint_as_float((bits >> 9) | 0x3f800000u) - 1.0f;
  return (u < 0.5f) ? 2.0f : 0.0f;
}

// ---------------- Edge dtype detect + canonicalize ----------------
__global__ __launch_bounds__(256) void detect_kernel(const int* __restrict__ ei,
                                                     int* __restrict__ found_nonzero) {
  int idx = blockIdx.x * 256 + threadIdx.x;  // 0..2047
  size_t j = (size_t)idx * 781;              // < 1.6M
  if (ei[2 * j + 1] != 0) atomicOr(found_nonzero, 1);
}

__global__ __launch_bounds__(256) void convert_kernel(const int* __restrict__ ei,
                                                      const int* __restrict__ found_nonzero,
                                                      int* __restrict__ row32,
                                                      int* __restrict__ col32) {
  int e = blockIdx.x * 256 + threadIdx.x;
  if (e >= N_EDGES) return;
  if (*found_nonzero) {  // int32 layout
    row32[e] = ei[e];
    col32[e] = ei[N_EDGES + e];
  } else {               // int64 layout: take low words
    row32[e] = ei[2 * (size_t)e];
    col32[e] = ei[2 * ((size_t)N_EDGES + (size_t)e)];
  }
}

// ---------------- Graph preprocessing ----------------
__global__ __launch_bounds__(256) void deg_kernel(const int* __restrict__ col,
                                                  int* __restrict__ deg) {
  int e = blockIdx.x * 256 + threadIdx.x;
  if (e < N_EDGES) atomicAdd(&deg[col[e]], 1);
}

__global__ __launch_bounds__(256) void dis_kernel(const int* __restrict__ deg,
                                                  float* __restrict__ dis) {
  int n = blockIdx.x * 256 + threadIdx.x;
  if (n < N_NODES) {
    int d = deg[n];
    dis[n] = (d > 0) ? (1.0f / sqrtf((float)d)) : 0.0f;
  }
}

// 3-phase parallel exclusive scan of deg -> rptr (N_NODES+1 entries)
#define SCAN_NB 391  // ceil(100000/256)
__global__ __launch_bounds__(256) void bsum_kernel(const int* __restrict__ deg,
                                                   int* __restrict__ bsum) {
  __shared__ int sh[256];
  int i = blockIdx.x * 256 + threadIdx.x;
  sh[threadIdx.x] = (i < N_NODES) ? deg[i] : 0;
  __syncthreads();
  for (int ofs = 128; ofs > 0; ofs >>= 1) {
    if (threadIdx.x < ofs) sh[threadIdx.x] += sh[threadIdx.x + ofs];
    __syncthreads();
  }
  if (threadIdx.x == 0) bsum[blockIdx.x] = sh[0];
}

__global__ __launch_bounds__(512) void bscan_kernel(const int* __restrict__ bsum,
                                                    int* __restrict__ boffs) {
  __shared__ int sh[512];
  int t = threadIdx.x;
  int v = (t < SCAN_NB) ? bsum[t] : 0;
  sh[t] = v;
  __syncthreads();
  for (int ofs = 1; ofs < 512; ofs <<= 1) {
    int u = (t >= ofs) ? sh[t - ofs] : 0;
    __syncthreads();
    sh[t] += u;
    __syncthreads();
  }
  if (t < SCAN_NB) boffs[t] = sh[t] - v;  // exclusive
  if (t == 0) boffs[SCAN_NB] = sh[SCAN_NB - 1];
}

__global__ __launch_bounds__(256) void rptr_kernel(const int* __restrict__ deg,
                                                   const int* __restrict__ boffs,
                                                   int* __restrict__ rptr) {
  __shared__ int sh[256];
  int i = blockIdx.x * 256 + threadIdx.x;
  int v = (i < N_NODES) ? deg[i] : 0;
  sh[threadIdx.x] = v;
  __syncthreads();
  for (int ofs = 1; ofs < 256; ofs <<= 1) {
    int u = (threadIdx.x >= ofs) ? sh[threadIdx.x - ofs] : 0;
    __syncthreads();
    sh[threadIdx.x] += u;
    __syncthreads();
  }
  if (i <= N_NODES) rptr[i] = boffs[blockIdx.x] + sh[threadIdx.x] - v;
}

__global__ __launch_bounds__(256) void fill_kernel(const int* __restrict__ row,
                                                   const int* __restrict__ col,
                                                   const float* __restrict__ dis,
                                                   const int* __restrict__ rptr,
                                                   int* cursor,
                                                   int* __restrict__ erow,
                                                   float* __restrict__ enorm) {
  int e = blockIdx.x * 256 + threadIdx.x;
  if (e < N_EDGES) {
    int c = col[e], r = row[e];
    int p = atomicAdd(&cursor[c], 1);
    int idx = rptr[c] + p;
    erow[idx] = r;
    enorm[idx] = dis[r] * dis[c];
  }
}

// ---------------- MFMA matmul: y_k = h @ W_k^T (+bias into y0) ----------------
// Split precision: A = hi+lo bf16 (exact), W = bf16 (RNE). D = Ahi*W + Alo*W.
// A-tile (64 x DIN) staged ONCE; loop over all NCH 64-col W chunks (W is
// L2-resident, ~256 KB) -> h fetched exactly once.
// YB: y1..y3 emitted bf16 (prop add/z operands); y0 always f32 (has bias).
template <int DIN, int LOG_DOUT, int NCH, bool YB>
__global__ __launch_bounds__(256) void matmul_mfma_kernel(
    const float* __restrict__ h, const float* __restrict__ W,
    const float* __restrict__ bias,
    float* __restrict__ y0, void* __restrict__ y1,
    void* __restrict__ y2, void* __restrict__ y3) {
  constexpr int LDK = DIN + 8;
  constexpr int DOUT = 1 << LOG_DOUT;
  __shared__ bf16_t sAhi[64 * LDK];
  __shared__ bf16_t sAlo[64 * LDK];
  __shared__ bf16_t sB[64 * LDK];
  const int m0 = blockIdx.x * 64;
  const int tid = threadIdx.x;

  constexpr int NLOAD = 64 * DIN / 4 / 256;
  union U4 { bf16_t b[4]; uint2 u; };
  for (int it = 0; it < NLOAD; ++it) {
    int idx = tid + it * 256;
    int r = idx / (DIN / 4);
    int cc = (idx % (DIN / 4)) * 4;
    int gm = m0 + r;
    float4 v = (gm < N_NODES) ? ((const float4*)h)[((size_t)gm * DIN + cc) >> 2]
                              : make_float4(0.f, 0.f, 0.f, 0.f);
    U4 hi, lo;
    hi.b[0] = (bf16_t)v.x; lo.b[0] = (bf16_t)(v.x - (float)hi.b[0]);
    hi.b[1] = (bf16_t)v.y; lo.b[1] = (bf16_t)(v.y - (float)hi.b[1]);
    hi.b[2] = (bf16_t)v.z; lo.b[2] = (bf16_t)(v.z - (float)hi.b[2]);
    hi.b[3] = (bf16_t)v.w; lo.b[3] = (bf16_t)(v.w - (float)hi.b[3]);
    *(uint2*)&sAhi[r * LDK + cc] = hi.u;
    *(uint2*)&sAlo[r * LDK + cc] = lo.u;
  }

  const int w = tid >> 6, lane = tid & 63;
  const int wm = w & 1, wn = w >> 1;
  const int quad = lane >> 4, lr = lane & 15;

  for (int nc = 0; nc < NCH; ++nc) {
    const int n0 = nc * 64;
    __syncthreads();  // protect sB from previous chunk's readers
    for (int it = 0; it < NLOAD; ++it) {
      int idx = tid + it * 256;
      int r = idx / (DIN / 4);
      int cc = (idx % (DIN / 4)) * 4;
      float4 v = ((const float4*)W)[((size_t)(n0 + r) * DIN + cc) >> 2];
      U4 wb;
      wb.b[0] = (bf16_t)v.x; wb.b[1] = (bf16_t)v.y;
      wb.b[2] = (bf16_t)v.z; wb.b[3] = (bf16_t)v.w;
      *(uint2*)&sB[r * LDK + cc] = wb.u;
    }
    __syncthreads();

    f32x4 acc[2][2] = {};
#pragma unroll
    for (int kt = 0; kt < DIN; kt += 32) {
      int koff = kt + quad * 8;
      bf16x8 ahi[2], alo[2], bfr[2];
#pragma unroll
      for (int mt = 0; mt < 2; ++mt) {
        int rowa = wm * 32 + mt * 16 + lr;
        ahi[mt] = *(const bf16x8*)&sAhi[rowa * LDK + koff];
        alo[mt] = *(const bf16x8*)&sAlo[rowa * LDK + koff];
      }
#pragma unroll
      for (int nt = 0; nt < 2; ++nt) {
        int rowb = wn * 32 + nt * 16 + lr;
        bfr[nt] = *(const bf16x8*)&sB[rowb * LDK + koff];
      }
#pragma unroll
      for (int mt = 0; mt < 2; ++mt)
#pragma unroll
        for (int nt = 0; nt < 2; ++nt) {
          acc[mt][nt] = mfma16(ahi[mt], bfr[nt], acc[mt][nt]);
          acc[mt][nt] = mfma16(alo[mt], bfr[nt], acc[mt][nt]);
        }
    }

    // D[row=quad*4+r][col=lr]; global col ng -> (k = ng>>LOG_DOUT, o = ng&(DOUT-1))
#pragma unroll
    for (int mt = 0; mt < 2; ++mt)
#pragma unroll
      for (int nt = 0; nt < 2; ++nt) {
        int ng = n0 + wn * 32 + nt * 16 + lr;
        int k = ng >> LOG_DOUT;
        int o = ng & (DOUT - 1);
        float badd = (k == 0) ? bias[o] : 0.f;
#pragma unroll
        for (int r = 0; r < 4; ++r) {
          int m = m0 + wm * 32 + mt * 16 + quad * 4 + r;
          if (m >= N_NODES) continue;
          float val = acc[mt][nt][r] + badd;
          size_t oi = (size_t)m * DOUT + o;
          if (k == 0) {
            y0[oi] = val;
          } else {
            void* yk = (k == 1) ? y1 : (k == 2) ? y2 : y3;
            if (YB) ((bf16_t*)yk)[oi] = (bf16_t)val;
            else    ((float*)yk)[oi]  = val;
          }
        }
      }
  }
}

// ---------------- Propagation: out[c] = sum_e norm*z[row_e] + add[c] ----------
// 2 features per lane. ZBF/ABF/OBF: z / add / out in bf16.
// EPI: 0 = none, 1 = dropout(key1), 2 = elu then dropout(key2)
template <int D, int EPI, bool ZBF, bool ABF, bool OBF>
__global__ __launch_bounds__(256) void prop_kernel(
    const void* __restrict__ zv, const void* __restrict__ addv,
    void* __restrict__ outv,
    const int* __restrict__ rptr, const int* __restrict__ erow,
    const float* __restrict__ enorm,
    uint32_t k0, uint32_t k1) {
  constexpr int LPN = D / 2;        // lanes per node (2 feats/lane)
  constexpr int NPB = 256 / LPN;    // nodes per block
  int lane = threadIdx.x % LPN;
  int nsub = threadIdx.x / LPN;
  int c = blockIdx.x * NPB + nsub;
  if (c >= N_NODES) return;
  int e0 = rptr[c], e1 = rptr[c + 1];
  float a0 = 0.f, a1 = 0.f;

  auto ld = [&](int r) -> float2 {
    if (ZBF) {
      bf16x2 v = ((const bf16x2*)zv)[(size_t)r * LPN + lane];
      return make_float2((float)v.x, (float)v.y);
    } else {
      return ((const float2*)zv)[(size_t)r * LPN + lane];
    }
  };

  int e = e0;
  for (; e + 3 < e1; e += 4) {
    int r0 = erow[e], r1 = erow[e + 1], r2 = erow[e + 2], r3 = erow[e + 3];
    float w0 = enorm[e], w1 = enorm[e + 1], w2 = enorm[e + 2], w3 = enorm[e + 3];
    float2 v0 = ld(r0), v1 = ld(r1), v2 = ld(r2), v3 = ld(r3);
    a0 = fmaf(w0, v0.x, a0); a1 = fmaf(w0, v0.y, a1);
    a0 = fmaf(w1, v1.x, a0); a1 = fmaf(w1, v1.y, a1);
    a0 = fmaf(w2, v2.x, a0); a1 = fmaf(w2, v2.y, a1);
    a0 = fmaf(w3, v3.x, a0); a1 = fmaf(w3, v3.y, a1);
  }
  for (; e < e1; ++e) {
    float wv = enorm[e];
    float2 v = ld(erow[e]);
    a0 = fmaf(wv, v.x, a0); a1 = fmaf(wv, v.y, a1);
  }

  size_t pidx = (size_t)c * LPN + lane;
  uint32_t fidx = (uint32_t)c * D + 2 * lane;
  float ax, ay;
  if (ABF) {
    bf16x2 av = ((const bf16x2*)addv)[pidx];
    ax = (float)av.x; ay = (float)av.y;
  } else {
    float2 av = ((const float2*)addv)[pidx];
    ax = av.x; ay = av.y;
  }
  float o0 = a0 + ax, o1 = a1 + ay;
  if (EPI == 1) {
    o0 *= drop_scale(fidx, k0, k1);
    o1 *= drop_scale(fidx + 1, k0, k1);
  }
  if (EPI == 2) {
    o0 = (o0 > 0.f) ? o0 : expm1f(o0);
    o1 = (o1 > 0.f) ? o1 : expm1f(o1);
    o0 *= drop_scale(fidx, k0, k1);
    o1 *= drop_scale(fidx + 1, k0, k1);
  }
  if (OBF) {
    bf16x2 bv;
    bv.x = (bf16_t)o0;
    bv.y = (bf16_t)o1;
    ((bf16x2*)outv)[pidx] = bv;
  } else {
    ((float2*)outv)[pidx] = make_float2(o0, o1);
  }
}

// ---------------- Launch ----------------
extern "C" void kernel_launch(void* const* d_in, const int* in_sizes, int n_in,
                              void* d_out, int out_size, void* d_ws, size_t ws_size,
                              hipStream_t stream) {
  const float* x  = (const float*)d_in[0];
  const int*   ei = (const int*)d_in[1];
  const float* W1 = (const float*)d_in[2];
  const float* b1 = (const float*)d_in[3];
  const float* W2 = (const float*)d_in[4];
  const float* b2 = (const float*)d_in[5];
  const float* W3 = (const float*)d_in[6];
  const float* b3 = (const float*)d_in[7];
  float* out = (float*)d_out;

  char* ws = (char*)d_ws;
  size_t off = 0;
  auto alloc = [&](size_t bytes) -> char* {
    char* p = ws + off;
    off += (bytes + 255) & ~(size_t)255;
    return p;
  };
  int*   flag   = (int*)alloc(256);
  int*   deg    = (int*)alloc((size_t)N_NODES * 4);
  int*   cursor = (int*)alloc((size_t)N_NODES * 4);
  float* dis    = (float*)alloc((size_t)N_NODES * 4);
  int*   rptr   = (int*)alloc((size_t)(N_NODES + 1) * 4);
  int*   bsum   = (int*)alloc((size_t)(SCAN_NB + 1) * 4);
  int*   boffs  = (int*)alloc((size_t)(SCAN_NB + 1) * 4);
  int*   row32  = (int*)alloc((size_t)N_EDGES * 4);
  int*   col32  = (int*)alloc((size_t)N_EDGES * 4);
  int*   erow   = (int*)alloc((size_t)N_EDGES * 4);
  float* enorm  = (float*)alloc((size_t)N_EDGES * 4);
  float*  R0  = (float*)alloc((size_t)N_NODES * 128 * 4);  // layer-1 y0 / out
  float*  R1  = (float*)alloc((size_t)N_NODES * 64 * 4);   // layer-2 y0 / out
  float*  R2  = (float*)alloc((size_t)N_NODES * 64 * 4);   // layer-3 z0..z3 (f32)
  bf16_t* Zb0 = (bf16_t*)alloc((size_t)N_NODES * 128 * 2);
  bf16_t* Zb1 = (bf16_t*)alloc((size_t)N_NODES * 128 * 2);
  bf16_t* Bb1 = (bf16_t*)alloc((size_t)N_NODES * 128 * 2);
  bf16_t* Bb2 = (bf16_t*)alloc((size_t)N_NODES * 128 * 2);

  hipMemsetAsync(flag, 0, 256, stream);
  hipMemsetAsync(deg, 0, (size_t)N_NODES * 4, stream);
  hipMemsetAsync(cursor, 0, (size_t)N_NODES * 4, stream);

  detect_kernel<<<8, 256, 0, stream>>>(ei, flag);
  convert_kernel<<<(N_EDGES + 255) / 256, 256, 0, stream>>>(ei, flag, row32, col32);
  deg_kernel<<<(N_EDGES + 255) / 256, 256, 0, stream>>>(col32, deg);
  dis_kernel<<<(N_NODES + 255) / 256, 256, 0, stream>>>(deg, dis);
  bsum_kernel<<<SCAN_NB, 256, 0, stream>>>(deg, bsum);
  bscan_kernel<<<1, 512, 0, stream>>>(bsum, boffs);
  rptr_kernel<<<SCAN_NB, 256, 0, stream>>>(deg, boffs, rptr);
  fill_kernel<<<(N_EDGES + 255) / 256, 256, 0, stream>>>(row32, col32, dis, rptr,
                                                         cursor, erow, enorm);

  // JAX partitionable split of key(42)=(0,42): subkey_i = threefry(key; 0, i)
  uint32_t d10, d11, d20, d21;
  threefry2x32(0u, 42u, 0u, 0u, d10, d11);  // dk1
  threefry2x32(0u, 42u, 0u, 1u, d20, d21);  // dk2

  const int MB = (N_NODES + 63) / 64;       // 1563
  const int PB4  = (N_NODES + 3) / 4;       // D=128 (NPB=4)
  const int PB8  = (N_NODES + 7) / 8;       // D=64  (NPB=8)
  const int PB32 = (N_NODES + 31) / 32;     // D=16  (NPB=32)

  // ---- Layer 1 (128 -> 128): Horner out = A(A(A y3 + y2) + y1) + y0 ; dropout1
  matmul_mfma_kernel<128, 7, 8, true><<<MB, 256, 0, stream>>>(
      x, W1, b1, R0, Bb1, Bb2, Zb0);
  prop_kernel<128, 0, true, true, true><<<PB4, 256, 0, stream>>>(
      Zb0, Bb2, Zb1, rptr, erow, enorm, 0, 0);
  prop_kernel<128, 0, true, true, true><<<PB4, 256, 0, stream>>>(
      Zb1, Bb1, Zb0, rptr, erow, enorm, 0, 0);
  prop_kernel<128, 1, true, false, false><<<PB4, 256, 0, stream>>>(
      Zb0, R0, R0, rptr, erow, enorm, d10, d11);
  // ---- Layer 2 (128 -> 64): h = R0; epilogue: elu + dropout2
  matmul_mfma_kernel<128, 6, 4, true><<<MB, 256, 0, stream>>>(
      R0, W2, b2, R1, Bb1, Bb2, Zb0);
  prop_kernel<64, 0, true, true, true><<<PB8, 256, 0, stream>>>(
      Zb0, Bb2, Zb1, rptr, erow, enorm, 0, 0);
  prop_kernel<64, 0, true, true, true><<<PB8, 256, 0, stream>>>(
      Zb1, Bb1, Zb0, rptr, erow, enorm, 0, 0);
  prop_kernel<64, 2, true, false, false><<<PB8, 256, 0, stream>>>(
      Zb0, R1, R1, rptr, erow, enorm, d20, d21);
  // ---- Layer 3 (64 -> 16): h = R1; final hop writes d_out (all f32)
  float* z0 = R2;
  float* z1 = R2 + (size_t)N_NODES * 16;
  float* z2 = R2 + (size_t)N_NODES * 32;
  float* z3 = R2 + (size_t)N_NODES * 48;
  matmul_mfma_kernel<64, 4, 1, false><<<MB, 256, 0, stream>>>(
      R1, W3, b3, z0, z1, z2, z3);
  prop_kernel<16, 0, false, false, false><<<PB32, 256, 0, stream>>>(
      z3, z2, z2, rptr, erow, enorm, 0, 0);
  prop_kernel<16, 0, false, false, false><<<PB32, 256, 0, stream>>>(
      z2, z1, z1, rptr, erow, enorm, 0, 0);
  prop_kernel<16, 0, false, false, false><<<PB32, 256, 0, stream>>>(
      z1, z0, out, rptr, erow, enorm, 0, 0);

  (void)in_sizes; (void)n_in; (void)out_size; (void)ws_size;
}